// Round 10
// baseline (1429.931 us; speedup 1.0000x reference)
//
#include <hip/hip_runtime.h>
#include <stdint.h>

// CIN layers: Xn[b,h,d] = sum_{j,k} W[h,j,k] * X0[b,j,d] * Xi[b,k,d] + bias[h]
// y[d,h] = sum_k Xi*W (mfma_32x32x16, A rows m=b'*16+d, B cols=32h), then
// Xacc += x0[b,j,d]*y.
// R19 post-mortem: chain-split REGRESSED (233->287us): doubled merge-FMA
// VALU (27->41%) + VGPR 252 (at cap) strangled scheduling; MfmaUtil FELL to
// 33.6. Dependent-MFMA latency is not the binder. Reverted to R18 structure.
// R20, two independent low-risk cuts on R18:
// (a) sliced accumulator: Xacc as 4x f32x4 quarters per P (static indices
//     only, rule #20); FMA each quarter directly against its ds-loaded f32x4
//     (shufflevector quarters of y = subregister reads) -> kills the f32x16
//     xsc assembly (16 movs/(s,P) if uncoalesced).
// (b) merged prep: all 4 prep kernels in ONE launch (branch on block range;
//     independent work) -> removes 3 launch gaps + 3 tail drains of the
//     72us total-minus-fused overhead.
// Everything else identical to R18 (j-major, W global->reg ping-pong, zero
// in-loop barriers, XROW=130 pad, f32 x0 factors).

#define NB_F0 39
#define NB_H  128
#define NB_B  4096
#define XROW 130   // padded k-row stride (shorts) for Xa/Xb

typedef float f32x4  __attribute__((ext_vector_type(4)));
typedef float f32x16 __attribute__((ext_vector_type(16)));
typedef short s16x8  __attribute__((ext_vector_type(8)));

template <int N> struct IC { static constexpr int value = N; };

__device__ __forceinline__ unsigned short rne_bf16(float f) {
  union { float f; unsigned u; } v; v.f = f;
  return (unsigned short)((v.u + 0x7fffu + ((v.u >> 16) & 1u)) >> 16);
}

// Merged prep (one launch):
//  blocks [0, NB_B): X0 f32 [B][39][16] -> X0T bf16 [B][16][64] (k=j pad) and
//    X0f f32 [B][39][16] d-PERMUTED (pos<->d swap bits 2,3) so a lane's 8 x0
//    factors for MFMA regs r=0..7 (d=(r&3)+8*((r>>2)&1)+4L) are contiguous.
//  remaining blocks: W f32 [128][39*Fi] -> Wf bf16 fragment-linear:
//    Wf[(((j*4+t)*KC16+c)*64+lane)*8+i] = W[h=t*32+(lane&31)][j, k=c*16+
//    (lane>>5)*8+i] (0 if k>=Fi), for W0 (KC16=4) then W1, W2 (KC16=8).
__global__ void prep_all_kernel(const float* __restrict__ X0g,
                                unsigned short* __restrict__ X0T,
                                float* __restrict__ X0f,
                                const float* __restrict__ W0s,
                                unsigned short* __restrict__ Wf0,
                                const float* __restrict__ W1s,
                                unsigned short* __restrict__ Wf1,
                                const float* __restrict__ W2s,
                                unsigned short* __restrict__ Wf2) {
  const int t = threadIdx.x;
  int blk = blockIdx.x;
  if (blk < NB_B) {
    const int b = blk;
    {
      const int d  = t >> 4;
      const int k4 = (t & 15) << 2;
      unsigned short vv[4];
#pragma unroll
      for (int i = 0; i < 4; ++i) {
        const int k = k4 + i;
        vv[i] = (k < NB_F0)
                    ? rne_bf16(X0g[(size_t)b * (NB_F0 * 16) + k * 16 + d])
                    : (unsigned short)0;
      }
      ushort4 pk; pk.x = vv[0]; pk.y = vv[1]; pk.z = vv[2]; pk.w = vv[3];
      *(ushort4*)&X0T[((size_t)b * 16 + d) * 64 + k4] = pk;
    }
    for (int idx = t; idx < NB_F0 * 16; idx += 256) {
      const int j = idx >> 4, pos = idx & 15;
      const int d =
          (pos & 3) | (((pos >> 3) & 1) << 2) | (((pos >> 2) & 1) << 3);
      X0f[(size_t)b * (NB_F0 * 16) + idx] =
          X0g[(size_t)b * (NB_F0 * 16) + j * 16 + d];
    }
    return;
  }
  blk -= NB_B;
  constexpr int TW0  = NB_F0 * 4 * 4 * 512;   // KC16=4
  constexpr int TW12 = NB_F0 * 4 * 8 * 512;   // KC16=8
  constexpr int NB0  = TW0 / 256;
  constexpr int NB12 = TW12 / 256;
  const float* Wsrc; unsigned short* Wdst; int Fi, kshift, idx;
  if (blk < NB0) {
    Wsrc = W0s; Wdst = Wf0; Fi = 39;  kshift = 2; idx = blk * 256 + t;
  } else if (blk < NB0 + NB12) {
    Wsrc = W1s; Wdst = Wf1; Fi = 128; kshift = 3;
    idx = (blk - NB0) * 256 + t;
  } else {
    Wsrc = W2s; Wdst = Wf2; Fi = 128; kshift = 3;
    idx = (blk - NB0 - NB12) * 256 + t;
  }
  const int i    = idx & 7;
  const int lane = (idx >> 3) & 63;
  const int c    = (idx >> 9) & ((1 << kshift) - 1);
  const int jt   = idx >> (9 + kshift);
  const int tt   = jt & 3;
  const int j    = jt >> 2;
  const int h = tt * 32 + (lane & 31);
  const int k = c * 16 + ((lane >> 5) << 3) + i;
  unsigned short v = 0;
  if (k < Fi) v = rne_bf16(Wsrc[(size_t)h * (NB_F0 * Fi) + j * Fi + k]);
  Wdst[idx] = v;
}

__global__ __launch_bounds__(256, 1) void cin_fused(
    const unsigned short* __restrict__ Wf0,
    const unsigned short* __restrict__ Wf1,
    const unsigned short* __restrict__ Wf2,
    const unsigned short* __restrict__ X0T,  // [B][16][64] bf16 (k zero-pad)
    const float* __restrict__ X0f,           // [B][39][16] f32, d-permuted
    const float* __restrict__ bias0,
    const float* __restrict__ bias1,
    const float* __restrict__ bias2,
    float* __restrict__ outp)                // [B][384]
{
  __shared__ __attribute__((aligned(16))) float x0f[4 * NB_F0 * 16];
  __shared__ __attribute__((aligned(16))) unsigned short Xa[4 * 16 * XROW];
  __shared__ __attribute__((aligned(16))) unsigned short Xb[4 * 16 * XROW];

  const int tid  = threadIdx.x;
  const int lane = tid & 63;
  const int wv   = tid >> 6;        // h-tile: h = wv*32 + col
  const int L    = lane >> 5;       // k-half selector within a 16-chunk
  const int col  = lane & 31;       // A row m / B col
  const int bblk = blockIdx.x * 4;  // 4 b per block

  // ---- stage x0 factors (f32 d-permuted, flat coalesced copy) ----
  {
    const float* src = X0f + (size_t)bblk * (NB_F0 * 16);
    for (int c = tid; c < (4 * NB_F0 * 16) / 4; c += 256)
      *(f32x4*)&x0f[c * 4] = *(const f32x4*)&src[c * 4];
  }
  __syncthreads();   // publish x0f

  const int x0base = L * 8;   // all waves share the block's 4 b (broadcast)

  // One CIN layer. KC16 = K-chunks (4 for Fi=64-pad, 8 for Fi=128);
  // AST = Xi A-fragment row stride in shorts (64 global X0T, XROW LDS).
  auto layer = [&](auto kc, auto ast, const unsigned short* __restrict__ Wl,
                   const unsigned short* af_base, const float* __restrict__ bv,
                   float* __restrict__ op, unsigned short* xn) {
    constexpr int KC16 = decltype(kc)::value;
    constexpr int AST  = decltype(ast)::value;

    // ---- Xi A-fragments: chain P covers b_local = 2P + (col>>4) ----
    s16x8 af[2][KC16];
#pragma unroll
    for (int P = 0; P < 2; ++P) {
      const unsigned short* base = af_base +
          (size_t)(2 * P + (col >> 4)) * (16 * AST) + (col & 15) * AST + L * 8;
#pragma unroll
      for (int c = 0; c < KC16; ++c) af[P][c] = *(const s16x8*)(base + c * 16);
    }

    // Accumulator as static-indexed f32x4 quarters: q = 2*bh + (m>>2),
    // element m&3; avoids any f32x16 xsc assembly (R20 change a).
    f32x4 Xq[2][4];
#pragma unroll
    for (int P = 0; P < 2; ++P)
#pragma unroll
      for (int q = 0; q < 4; ++q) Xq[P][q] = (f32x4)(0.f);

    f32x16 kZero;
#pragma unroll
    for (int r = 0; r < 16; ++r) kZero[r] = 0.f;

    // ---- W fragments straight from global (L2-hot) into registers ----
    const s16x8* __restrict__ W8 = (const s16x8*)Wl;
    auto wload = [&](int j, s16x8 (&w)[KC16]) {
      const s16x8* p = W8 + ((size_t)(j * 4 + wv) * KC16) * 64 + lane;
#pragma unroll
      for (int c = 0; c < KC16; ++c) w[c] = p[c * 64];
    };

    auto compute = [&](int s, const s16x8 (&w)[KC16]) {
#pragma unroll
      for (int P = 0; P < 2; ++P) {
        f32x16 y = __builtin_amdgcn_mfma_f32_32x32x16_bf16(af[P][0], w[0],
                                                           kZero, 0, 0, 0);
#pragma unroll
        for (int c = 1; c < KC16; ++c)
          y = __builtin_amdgcn_mfma_f32_32x32x16_bf16(af[P][c], w[c], y,
                                                      0, 0, 0);
        // x0 scale: quarter q of the 16 acc regs <- f32x4 a_q; FMA each
        // quarter directly (shufflevector = subregister read, no movs).
        const float* xr0 = &x0f[x0base + (2 * P + 0) * (NB_F0 * 16) + s * 16];
        const float* xr1 = &x0f[x0base + (2 * P + 1) * (NB_F0 * 16) + s * 16];
        const f32x4 a0 = *(const f32x4*)(xr0);
        const f32x4 a1 = *(const f32x4*)(xr0 + 4);
        const f32x4 a2 = *(const f32x4*)(xr1);
        const f32x4 a3 = *(const f32x4*)(xr1 + 4);
        const f32x4 y0 = __builtin_shufflevector(y, y, 0, 1, 2, 3);
        const f32x4 y1 = __builtin_shufflevector(y, y, 4, 5, 6, 7);
        const f32x4 y2 = __builtin_shufflevector(y, y, 8, 9, 10, 11);
        const f32x4 y3 = __builtin_shufflevector(y, y, 12, 13, 14, 15);
        Xq[P][0] = __builtin_elementwise_fma(a0, y0, Xq[P][0]);
        Xq[P][1] = __builtin_elementwise_fma(a1, y1, Xq[P][1]);
        Xq[P][2] = __builtin_elementwise_fma(a2, y2, Xq[P][2]);
        Xq[P][3] = __builtin_elementwise_fma(a3, y3, Xq[P][3]);
      }
    };

    // ---- barrier-free main loop: W reg ping-pong, 1-stage prefetch ----
    s16x8 wA[KC16], wB[KC16];
    wload(0, wA);
    wload(1, wB);
    int s = 0;
    for (; s + 2 <= NB_F0; s += 2) {
      compute(s, wA);
      wload(s + 2 < NB_F0 ? s + 2 : 0, wA);   // reissue post-use (reg WAR ok)
      compute(s + 1, wB);
      if (s + 3 < NB_F0) wload(s + 3, wB);
    }
    if (s < NB_F0) compute(s, wA);   // odd tail (S=39)

    // ---- epilogue: sums to global; Xn to LDS in A-fragment layout ----
    const float bias_v = bv[wv * 32 + col];
#pragma unroll
    for (int P = 0; P < 2; ++P) {
#pragma unroll
      for (int bh = 0; bh < 2; ++bh) {
        const int bl = 2 * P + bh;
        float v[8];
#pragma unroll
        for (int m = 0; m < 8; ++m)
          v[m] = Xq[P][2 * bh + (m >> 2)][m & 3] + bias_v;
        if (xn) {
#pragma unroll
          for (int m = 0; m < 8; ++m) {
            const int d = (m & 3) + 8 * ((m >> 2) & 1) + 4 * L;
            xn[(bl * 16 + d) * XROW + wv * 32 + col] = rne_bf16(v[m]);
          }
        }
        float tot = ((v[0] + v[1]) + (v[2] + v[3])) +
                    ((v[4] + v[5]) + (v[6] + v[7]));
        tot += __shfl_xor(tot, 32);
        if (lane < 32) op[(size_t)(bblk + bl) * 384 + wv * 32 + lane] = tot;
      }
    }
  };

  layer(IC<4>{}, IC<64>{}, Wf0, X0T + (size_t)bblk * (16 * 64),
        bias0, outp + 0, Xa);
  __syncthreads();   // publish X1 before L1 af reads
  layer(IC<8>{}, IC<XROW>{}, Wf1, Xa, bias1, outp + 128, Xb);
  __syncthreads();   // publish X2 before L2 af reads
  layer(IC<8>{}, IC<XROW>{}, Wf2, Xb, bias2, outp + 256,
        (unsigned short*)nullptr);
}

extern "C" void kernel_launch(void* const* d_in, const int* in_sizes, int n_in,
                              void* d_out, int out_size, void* d_ws, size_t ws_size,
                              hipStream_t stream) {
  (void)in_sizes; (void)n_in; (void)out_size; (void)ws_size;
  const float* X0g = (const float*)d_in[0];
  const float* W0  = (const float*)d_in[1];
  const float* b0  = (const float*)d_in[2];
  const float* W1  = (const float*)d_in[3];
  const float* b1  = (const float*)d_in[4];
  const float* W2  = (const float*)d_in[5];
  const float* b2  = (const float*)d_in[6];
  float* out = (float*)d_out;

  char* p = (char*)d_ws;
  unsigned short* X0T = (unsigned short*)p; p += (size_t)NB_B * 16 * 64 * 2;
  float*          X0f = (float*)p;          p += (size_t)NB_B * NB_F0 * 16 * 4;
  unsigned short* Wf0 = (unsigned short*)p; p += (size_t)NB_F0 * 4 * 4 * 512 * 2;
  unsigned short* Wf1 = (unsigned short*)p; p += (size_t)NB_F0 * 4 * 8 * 512 * 2;
  unsigned short* Wf2 = (unsigned short*)p; p += (size_t)NB_F0 * 4 * 8 * 512 * 2;

  constexpr int TW0  = NB_F0 * 4 * 4 * 512;
  constexpr int TW12 = NB_F0 * 4 * 8 * 512;
  const int prep_blocks = NB_B + TW0 / 256 + 2 * (TW12 / 256);
  hipLaunchKernelGGL(prep_all_kernel, dim3(prep_blocks), dim3(256), 0, stream,
                     X0g, X0T, X0f, W0, Wf0, W1, Wf1, W2, Wf2);

  hipLaunchKernelGGL(cin_fused, dim3(NB_B / 4), dim3(256), 0, stream,
                     Wf0, Wf1, Wf2, X0T, X0f, b0, b1, b2, out);
}

// Round 11
// 296.547 us; speedup vs baseline: 4.8219x; 4.8219x over previous
//
#include <hip/hip_runtime.h>
#include <stdint.h>

// CIN layers: Xn[b,h,d] = sum_{j,k} W[h,j,k] * X0[b,j,d] * Xi[b,k,d] + bias[h]
// y[d,h] = sum_k Xi*W (mfma_32x32x16, A rows m=b'*16+d, B cols=32h), then
// Xacc += x0[b,j,d]*y.
// R20 post-mortem: sliced-accumulator (a) spilled catastrophically (VGPR 256,
// 3.3GB scratch traffic/dispatch, 1387us): shufflevector quarters of the
// f32x16 MFMA result + 8 separate f32x4 accumulators exploded live state.
// "Subregister read is free" was WRONG for MFMA results. Merged prep (b) is
// verified fine (all spill traffic was in cin_fused).
// R21 = R18 compute VERBATIM (f32x16 xsc + single elementwise_fma, VGPR 188,
// 233us fused -- best measured) + R20's merged single-launch prep (removes
// 3 launch gaps + 3 tail drains). Lock-in round: isolates (b)'s gain.
// Structure: fused 3 layers, Xn via LDS (XROW=130 pad, 0 conflicts), f32 x0
// factors, j-major, W global->reg ping-pong, zero in-loop barriers.

#define NB_F0 39
#define NB_H  128
#define NB_B  4096
#define XROW 130   // padded k-row stride (shorts) for Xa/Xb

typedef float f32x4  __attribute__((ext_vector_type(4)));
typedef float f32x16 __attribute__((ext_vector_type(16)));
typedef short s16x8  __attribute__((ext_vector_type(8)));

template <int N> struct IC { static constexpr int value = N; };

__device__ __forceinline__ unsigned short rne_bf16(float f) {
  union { float f; unsigned u; } v; v.f = f;
  return (unsigned short)((v.u + 0x7fffu + ((v.u >> 16) & 1u)) >> 16);
}

// Merged prep (one launch):
//  blocks [0, NB_B): X0 f32 [B][39][16] -> X0T bf16 [B][16][64] (k=j pad) and
//    X0f f32 [B][39][16] d-PERMUTED (pos<->d swap bits 2,3) so a lane's 8 x0
//    factors for MFMA regs r=0..7 (d=(r&3)+8*((r>>2)&1)+4L) are contiguous.
//  remaining blocks: W f32 [128][39*Fi] -> Wf bf16 fragment-linear:
//    Wf[(((j*4+t)*KC16+c)*64+lane)*8+i] = W[h=t*32+(lane&31)][j, k=c*16+
//    (lane>>5)*8+i] (0 if k>=Fi), for W0 (KC16=4) then W1, W2 (KC16=8).
__global__ void prep_all_kernel(const float* __restrict__ X0g,
                                unsigned short* __restrict__ X0T,
                                float* __restrict__ X0f,
                                const float* __restrict__ W0s,
                                unsigned short* __restrict__ Wf0,
                                const float* __restrict__ W1s,
                                unsigned short* __restrict__ Wf1,
                                const float* __restrict__ W2s,
                                unsigned short* __restrict__ Wf2) {
  const int t = threadIdx.x;
  int blk = blockIdx.x;
  if (blk < NB_B) {
    const int b = blk;
    {
      const int d  = t >> 4;
      const int k4 = (t & 15) << 2;
      unsigned short vv[4];
#pragma unroll
      for (int i = 0; i < 4; ++i) {
        const int k = k4 + i;
        vv[i] = (k < NB_F0)
                    ? rne_bf16(X0g[(size_t)b * (NB_F0 * 16) + k * 16 + d])
                    : (unsigned short)0;
      }
      ushort4 pk; pk.x = vv[0]; pk.y = vv[1]; pk.z = vv[2]; pk.w = vv[3];
      *(ushort4*)&X0T[((size_t)b * 16 + d) * 64 + k4] = pk;
    }
    for (int idx = t; idx < NB_F0 * 16; idx += 256) {
      const int j = idx >> 4, pos = idx & 15;
      const int d =
          (pos & 3) | (((pos >> 3) & 1) << 2) | (((pos >> 2) & 1) << 3);
      X0f[(size_t)b * (NB_F0 * 16) + idx] =
          X0g[(size_t)b * (NB_F0 * 16) + j * 16 + d];
    }
    return;
  }
  blk -= NB_B;
  constexpr int TW0  = NB_F0 * 4 * 4 * 512;   // KC16=4
  constexpr int TW12 = NB_F0 * 4 * 8 * 512;   // KC16=8
  constexpr int NB0  = TW0 / 256;
  constexpr int NB12 = TW12 / 256;
  const float* Wsrc; unsigned short* Wdst; int Fi, kshift, idx;
  if (blk < NB0) {
    Wsrc = W0s; Wdst = Wf0; Fi = 39;  kshift = 2; idx = blk * 256 + t;
  } else if (blk < NB0 + NB12) {
    Wsrc = W1s; Wdst = Wf1; Fi = 128; kshift = 3;
    idx = (blk - NB0) * 256 + t;
  } else {
    Wsrc = W2s; Wdst = Wf2; Fi = 128; kshift = 3;
    idx = (blk - NB0 - NB12) * 256 + t;
  }
  const int i    = idx & 7;
  const int lane = (idx >> 3) & 63;
  const int c    = (idx >> 9) & ((1 << kshift) - 1);
  const int jt   = idx >> (9 + kshift);
  const int tt   = jt & 3;
  const int j    = jt >> 2;
  const int h = tt * 32 + (lane & 31);
  const int k = c * 16 + ((lane >> 5) << 3) + i;
  unsigned short v = 0;
  if (k < Fi) v = rne_bf16(Wsrc[(size_t)h * (NB_F0 * Fi) + j * Fi + k]);
  Wdst[idx] = v;
}

__global__ __launch_bounds__(256, 1) void cin_fused(
    const unsigned short* __restrict__ Wf0,
    const unsigned short* __restrict__ Wf1,
    const unsigned short* __restrict__ Wf2,
    const unsigned short* __restrict__ X0T,  // [B][16][64] bf16 (k zero-pad)
    const float* __restrict__ X0f,           // [B][39][16] f32, d-permuted
    const float* __restrict__ bias0,
    const float* __restrict__ bias1,
    const float* __restrict__ bias2,
    float* __restrict__ outp)                // [B][384]
{
  __shared__ __attribute__((aligned(16))) float x0f[4 * NB_F0 * 16];
  __shared__ __attribute__((aligned(16))) unsigned short Xa[4 * 16 * XROW];
  __shared__ __attribute__((aligned(16))) unsigned short Xb[4 * 16 * XROW];

  const int tid  = threadIdx.x;
  const int lane = tid & 63;
  const int wv   = tid >> 6;        // h-tile: h = wv*32 + col
  const int L    = lane >> 5;       // k-half selector within a 16-chunk
  const int col  = lane & 31;       // A row m / B col
  const int bblk = blockIdx.x * 4;  // 4 b per block

  // ---- stage x0 factors (f32 d-permuted, flat coalesced copy) ----
  {
    const float* src = X0f + (size_t)bblk * (NB_F0 * 16);
    for (int c = tid; c < (4 * NB_F0 * 16) / 4; c += 256)
      *(f32x4*)&x0f[c * 4] = *(const f32x4*)&src[c * 4];
  }
  __syncthreads();   // publish x0f

  const int x0base = L * 8;   // all waves share the block's 4 b (broadcast)

  // One CIN layer. KC16 = K-chunks (4 for Fi=64-pad, 8 for Fi=128);
  // AST = Xi A-fragment row stride in shorts (64 global X0T, XROW LDS).
  auto layer = [&](auto kc, auto ast, const unsigned short* __restrict__ Wl,
                   const unsigned short* af_base, const float* __restrict__ bv,
                   float* __restrict__ op, unsigned short* xn) {
    constexpr int KC16 = decltype(kc)::value;
    constexpr int AST  = decltype(ast)::value;

    // ---- Xi A-fragments: chain P covers b_local = 2P + (col>>4) ----
    s16x8 af[2][KC16];
#pragma unroll
    for (int P = 0; P < 2; ++P) {
      const unsigned short* base = af_base +
          (size_t)(2 * P + (col >> 4)) * (16 * AST) + (col & 15) * AST + L * 8;
#pragma unroll
      for (int c = 0; c < KC16; ++c) af[P][c] = *(const s16x8*)(base + c * 16);
    }

    f32x16 Xacc[2], kZero;
#pragma unroll
    for (int r = 0; r < 16; ++r) kZero[r] = 0.f;
#pragma unroll
    for (int P = 0; P < 2; ++P) Xacc[P] = kZero;

    // ---- W fragments straight from global (L2-hot) into registers ----
    const s16x8* __restrict__ W8 = (const s16x8*)Wl;
    auto wload = [&](int j, s16x8 (&w)[KC16]) {
      const s16x8* p = W8 + ((size_t)(j * 4 + wv) * KC16) * 64 + lane;
#pragma unroll
      for (int c = 0; c < KC16; ++c) w[c] = p[c * 64];
    };

    auto compute = [&](int s, const s16x8 (&w)[KC16]) {
#pragma unroll
      for (int P = 0; P < 2; ++P) {
        f32x16 y = __builtin_amdgcn_mfma_f32_32x32x16_bf16(af[P][0], w[0],
                                                           kZero, 0, 0, 0);
#pragma unroll
        for (int c = 1; c < KC16; ++c)
          y = __builtin_amdgcn_mfma_f32_32x32x16_bf16(af[P][c], w[c], y,
                                                      0, 0, 0);
        // x0 scale: regs 0-7 <- b'=2P (this lane's L 8-run), 8-15 <- 2P+1.
        // f32 factors: broadcast ds_read_b128 x4, zero unpack VALU.
        const float* xr0 = &x0f[x0base + (2 * P + 0) * (NB_F0 * 16) + s * 16];
        const float* xr1 = &x0f[x0base + (2 * P + 1) * (NB_F0 * 16) + s * 16];
        const f32x4 a0 = *(const f32x4*)(xr0);
        const f32x4 a1 = *(const f32x4*)(xr0 + 4);
        const f32x4 a2 = *(const f32x4*)(xr1);
        const f32x4 a3 = *(const f32x4*)(xr1 + 4);
        f32x16 xsc;
#pragma unroll
        for (int i = 0; i < 4; ++i) {
          xsc[i]      = a0[i];
          xsc[4 + i]  = a1[i];
          xsc[8 + i]  = a2[i];
          xsc[12 + i] = a3[i];
        }
        Xacc[P] = __builtin_elementwise_fma(xsc, y, Xacc[P]);
      }
    };

    // ---- barrier-free main loop: W reg ping-pong, 1-stage prefetch ----
    s16x8 wA[KC16], wB[KC16];
    wload(0, wA);
    wload(1, wB);
    int s = 0;
    for (; s + 2 <= NB_F0; s += 2) {
      compute(s, wA);
      wload(s + 2 < NB_F0 ? s + 2 : 0, wA);   // reissue post-use (reg WAR ok)
      compute(s + 1, wB);
      if (s + 3 < NB_F0) wload(s + 3, wB);
    }
    if (s < NB_F0) compute(s, wA);   // odd tail (S=39)

    // ---- epilogue: sums to global; Xn to LDS in A-fragment layout ----
    const float bias_v = bv[wv * 32 + col];
#pragma unroll
    for (int P = 0; P < 2; ++P) {
#pragma unroll
      for (int bh = 0; bh < 2; ++bh) {
        const int bl = 2 * P + bh;
        float v[8];
#pragma unroll
        for (int m = 0; m < 8; ++m) v[m] = Xacc[P][bh * 8 + m] + bias_v;
        if (xn) {
#pragma unroll
          for (int m = 0; m < 8; ++m) {
            const int d = (m & 3) + 8 * ((m >> 2) & 1) + 4 * L;
            xn[(bl * 16 + d) * XROW + wv * 32 + col] = rne_bf16(v[m]);
          }
        }
        float tot = ((v[0] + v[1]) + (v[2] + v[3])) +
                    ((v[4] + v[5]) + (v[6] + v[7]));
        tot += __shfl_xor(tot, 32);
        if (lane < 32) op[(size_t)(bblk + bl) * 384 + wv * 32 + lane] = tot;
      }
    }
  };

  layer(IC<4>{}, IC<64>{}, Wf0, X0T + (size_t)bblk * (16 * 64),
        bias0, outp + 0, Xa);
  __syncthreads();   // publish X1 before L1 af reads
  layer(IC<8>{}, IC<XROW>{}, Wf1, Xa, bias1, outp + 128, Xb);
  __syncthreads();   // publish X2 before L2 af reads
  layer(IC<8>{}, IC<XROW>{}, Wf2, Xb, bias2, outp + 256,
        (unsigned short*)nullptr);
}

extern "C" void kernel_launch(void* const* d_in, const int* in_sizes, int n_in,
                              void* d_out, int out_size, void* d_ws, size_t ws_size,
                              hipStream_t stream) {
  (void)in_sizes; (void)n_in; (void)out_size; (void)ws_size;
  const float* X0g = (const float*)d_in[0];
  const float* W0  = (const float*)d_in[1];
  const float* b0  = (const float*)d_in[2];
  const float* W1  = (const float*)d_in[3];
  const float* b1  = (const float*)d_in[4];
  const float* W2  = (const float*)d_in[5];
  const float* b2  = (const float*)d_in[6];
  float* out = (float*)d_out;

  char* p = (char*)d_ws;
  unsigned short* X0T = (unsigned short*)p; p += (size_t)NB_B * 16 * 64 * 2;
  float*          X0f = (float*)p;          p += (size_t)NB_B * NB_F0 * 16 * 4;
  unsigned short* Wf0 = (unsigned short*)p; p += (size_t)NB_F0 * 4 * 4 * 512 * 2;
  unsigned short* Wf1 = (unsigned short*)p; p += (size_t)NB_F0 * 4 * 8 * 512 * 2;
  unsigned short* Wf2 = (unsigned short*)p; p += (size_t)NB_F0 * 4 * 8 * 512 * 2;

  constexpr int TW0  = NB_F0 * 4 * 4 * 512;
  constexpr int TW12 = NB_F0 * 4 * 8 * 512;
  const int prep_blocks = NB_B + TW0 / 256 + 2 * (TW12 / 256);
  hipLaunchKernelGGL(prep_all_kernel, dim3(prep_blocks), dim3(256), 0, stream,
                     X0g, X0T, X0f, W0, Wf0, W1, Wf1, W2, Wf2);

  hipLaunchKernelGGL(cin_fused, dim3(NB_B / 4), dim3(256), 0, stream,
                     Wf0, Wf1, Wf2, X0T, X0f, b0, b1, b2, out);
}